// Round 2
// baseline (20721.463 us; speedup 1.0000x reference)
//
#include <hip/hip_runtime.h>
#include <hip/hip_bf16.h>

#define B_ 128
#define T_ 512
#define DIM_ 256
#define E_ 512
#define H_ 512
#define NB_ 32        // blocks per batch-group (sync domain)
#define NG_ 8         // batch groups
#define WROW 1032     // padded LDS row stride (1024 + 8) in bf16 elems

typedef __attribute__((ext_vector_type(8))) short short8;
typedef __attribute__((ext_vector_type(4))) float floatx4;

__device__ __forceinline__ float sigmoidf_(float x) {
  return 1.0f / (1.0f + __expf(-x));
}

__device__ __forceinline__ short f2bs(float f) {
  __hip_bfloat16 h = __float2bfloat16(f);
  return *reinterpret_cast<short*>(&h);
}

// ---------------------------------------------------------------------------
// Kernel 0: convert We (fp32) -> bf16 workspace copy.
// ---------------------------------------------------------------------------
__global__ __launch_bounds__(256) void cvt_we(const float* __restrict__ src,
                                              __hip_bfloat16* __restrict__ dst,
                                              int n) {
  int i = blockIdx.x * 256 + threadIdx.x;
  if (i < n) dst[i] = __float2bfloat16(src[i]);
}

// ---------------------------------------------------------------------------
// Kernel 1: xe[b*T+t][e] = sum_d x_t[b,t,d] * We[e,d] + be[e]   (bf16 out)
// Block: 256 thr = 4 waves. Block tile 32(M) x 512(N). Wave: 16M x 256N.
// A (x_t) fp32 converted inline; W pre-converted bf16 (Web).
// ---------------------------------------------------------------------------
__global__ __launch_bounds__(256) void embed_gemm(
    const float* __restrict__ A,             // x_t  [65536][256] fp32
    const __hip_bfloat16* __restrict__ W,    // Web  [512][256] bf16
    const float* __restrict__ bias,          // be   [512] fp32
    __hip_bfloat16* __restrict__ C)          // xe   [65536][512] bf16
{
  const int tid = threadIdx.x;
  const int lane = tid & 63;
  const int w = tid >> 6;
  const int q = lane >> 4;
  const int l15 = lane & 15;
  const int m0 = blockIdx.x * 32 + (w >> 1) * 16;
  const int n0 = (w & 1) * 256;

  const float* a_base = A + (size_t)(m0 + l15) * DIM_ + q * 8;

  floatx4 acc[16];
#pragma unroll
  for (int j = 0; j < 16; ++j) acc[j] = (floatx4){0.f, 0.f, 0.f, 0.f};

  for (int ks = 0; ks < 8; ++ks) {
    const float* ap = a_base + ks * 32;
    short8 a;
#pragma unroll
    for (int j = 0; j < 8; ++j) a[j] = f2bs(ap[j]);
    short8 bf[16];
#pragma unroll
    for (int j = 0; j < 16; ++j) {
      const short* b_ptr =
          (const short*)W + (n0 + j * 16 + l15) * DIM_ + ks * 32 + q * 8;
      bf[j] = *(const short8*)b_ptr;
    }
#pragma unroll
    for (int j = 0; j < 16; ++j)
      acc[j] = __builtin_amdgcn_mfma_f32_16x16x32_bf16(a, bf[j], acc[j], 0, 0, 0);
  }

#pragma unroll
  for (int j = 0; j < 16; ++j) {
    const int col = n0 + j * 16 + l15;
    const float bv = bias[col];
#pragma unroll
    for (int r = 0; r < 4; ++r) {
      const int row = m0 + q * 4 + r;
      C[(size_t)row * E_ + col] = __float2bfloat16(acc[j][r] + bv);
    }
  }
}

// ---------------------------------------------------------------------------
// Kernel 2: persistent LSTM. 256 blocks (1/CU), 256 thr.
// block = (group g = blk&7, slice jb = blk>>3): batches [g*16,g*16+16),
// dims [jb*16, jb*16+16), all 4 gates. Weights [64 rows x 1024 K] in LDS
// (converted fp32->bf16 at fill).
// Wave w handles K-range [w*256,(w+1)*256): waves 0,1 -> xe (W), 2,3 -> h (R).
// ---------------------------------------------------------------------------
__global__ __launch_bounds__(256, 1) void lstm_persist(
    const float* __restrict__ h0,
    const float* __restrict__ c0,
    const float* __restrict__ Wi_, const float* __restrict__ bi_,
    const float* __restrict__ Wf_, const float* __restrict__ bf_,
    const float* __restrict__ Wg_, const float* __restrict__ bg_,
    const float* __restrict__ Wo_, const float* __restrict__ bo_,
    const float* __restrict__ Ri_, const float* __restrict__ Rf_,
    const float* __restrict__ Rg_, const float* __restrict__ Ro_,
    const __hip_bfloat16* __restrict__ xe,   // [B*T][E] bf16
    __hip_bfloat16* __restrict__ hbuf,       // [2][B][H] bf16
    unsigned* __restrict__ cnt,              // group counters, stride 64 uints
    float* __restrict__ out)                 // hidden_seq | h_last | c_last
{
  extern __shared__ short wts[];             // 64 * WROW bf16 = 132096 B
  __shared__ float pbuf[4][4][16][16];       // [wave][gate][m][n] partials
  __shared__ float cbuf[16][16];             // fp32 cell state slice
  __shared__ float bias_s[4][16];

  const int tid = threadIdx.x;
  const int lane = tid & 63;
  const int w = tid >> 6;
  const int q = lane >> 4;
  const int l15 = lane & 15;
  const int blk = blockIdx.x;
  const int g = blk & 7;        // batch group (XCD-affinity heuristic)
  const int jb = blk >> 3;      // dim slice
  const int b0 = g * 16;
  const int d0 = jb * 16;
  unsigned* cnt_g = cnt + g * 64;

  const float* Wp[4] = {Wi_, Wf_, Wg_, Wo_};
  const float* Rp[4] = {Ri_, Rf_, Rg_, Ro_};
  const float* bp[4] = {bi_, bf_, bg_, bo_};

  // ---- load weights into LDS: row (G*16+dl) = [W_G[d0+dl][0:512] | R_G[...]]
  // 64 rows x 1024 elems, 8 elems per store -> 64*128 chunks.
  for (int idx = tid; idx < 64 * 128; idx += 256) {
    const int row = idx >> 7;
    const int ch = idx & 127;
    const int G = row >> 4, dl = row & 15;
    const int k = ch * 8;
    const float* src = (k < 512) ? Wp[G] + (d0 + dl) * E_ + k
                                 : Rp[G] + (d0 + dl) * H_ + (k - 512);
    short8 v;
#pragma unroll
    for (int s = 0; s < 8; ++s) v[s] = f2bs(src[s]);
    *(short8*)&wts[row * WROW + k] = v;
  }
  if (tid < 64) {
    const int G = tid >> 4, n = tid & 15;
    bias_s[G][n] = bp[G][d0 + n];
  }
  {
    const int m = tid >> 4, n = tid & 15;
    cbuf[m][n] = c0[(b0 + m) * H_ + d0 + n];
  }
  // h0 -> hbuf[0] bf16 (whole array cooperatively: 256 blocks * 256 thr)
  hbuf[blk * 256 + tid] = __float2bfloat16(h0[blk * 256 + tid]);
  __syncthreads();

#define GROUP_BARRIER(target)                                                 \
  do {                                                                        \
    __threadfence();                                                          \
    __syncthreads();                                                          \
    if (tid == 0) {                                                           \
      __hip_atomic_fetch_add(cnt_g, 1u, __ATOMIC_RELEASE,                     \
                             __HIP_MEMORY_SCOPE_AGENT);                       \
      while (__hip_atomic_load(cnt_g, __ATOMIC_RELAXED,                       \
                               __HIP_MEMORY_SCOPE_AGENT) < (unsigned)(target))\
        __builtin_amdgcn_s_sleep(1);                                          \
    }                                                                         \
    __syncthreads();                                                          \
    __threadfence();                                                          \
  } while (0)

  GROUP_BARRIER(NB_);  // h0 visible to whole group

  // per-wave pointers
  const short* xbase = (const short*)xe +
      (size_t)(b0 + l15) * T_ * E_ + w * 256 + q * 8;        // valid for w<2
  const int lds_base = l15 * WROW + w * 256 + q * 8;

  short8 cur[8];
  if (w < 2) {
#pragma unroll
    for (int s = 0; s < 8; ++s) cur[s] = *(const short8*)(xbase + s * 32);
  }

  for (int t = 0; t < T_; ++t) {
    if (w >= 2) {
      const short* hb = (const short*)hbuf + (t & 1) * (B_ * H_) +
                        (b0 + l15) * H_ + (w - 2) * 256 + q * 8;
#pragma unroll
      for (int s = 0; s < 8; ++s) cur[s] = *(const short8*)(hb + s * 32);
    }

    floatx4 acc[4];
#pragma unroll
    for (int G = 0; G < 4; ++G) acc[G] = (floatx4){0.f, 0.f, 0.f, 0.f};

#pragma unroll
    for (int s = 0; s < 8; ++s) {
#pragma unroll
      for (int G = 0; G < 4; ++G) {
        short8 b = *(const short8*)&wts[G * 16 * WROW + lds_base + s * 32];
        acc[G] = __builtin_amdgcn_mfma_f32_16x16x32_bf16(cur[s], b, acc[G], 0, 0, 0);
      }
    }

    // prefetch next step's xe fragments (read-only: safe across barrier)
    if (w < 2 && t + 1 < T_) {
      const short* xp = xbase + (size_t)(t + 1) * E_;
#pragma unroll
      for (int s = 0; s < 8; ++s) cur[s] = *(const short8*)(xp + s * 32);
    }

    // write partial sums to LDS
#pragma unroll
    for (int G = 0; G < 4; ++G)
#pragma unroll
      for (int r = 0; r < 4; ++r)
        pbuf[w][G][q * 4 + r][l15] = acc[G][r];
    __syncthreads();

    // combine + activations: thread tid -> (m = tid>>4, n = tid&15)
    {
      const int m = tid >> 4, n = tid & 15;
      float pre[4];
#pragma unroll
      for (int G = 0; G < 4; ++G)
        pre[G] = pbuf[0][G][m][n] + pbuf[1][G][m][n] + pbuf[2][G][m][n] +
                 pbuf[3][G][m][n] + bias_s[G][n];
      const float iv = sigmoidf_(pre[0]);
      const float fv = sigmoidf_(pre[1]);
      const float gv = tanhf(pre[2]);
      const float ov = sigmoidf_(pre[3]);
      const float c = gv * iv + fv * cbuf[m][n];
      cbuf[m][n] = c;
      const float h = ov * tanhf(c);
      hbuf[((t + 1) & 1) * (B_ * H_) + (b0 + m) * H_ + d0 + n] =
          __float2bfloat16(h);
      out[((size_t)(b0 + m) * T_ + t) * H_ + d0 + n] = h;
      if (t == T_ - 1) {
        out[(size_t)B_ * T_ * H_ + (b0 + m) * H_ + d0 + n] = h;
        out[(size_t)B_ * T_ * H_ + B_ * H_ + (b0 + m) * H_ + d0 + n] = c;
      }
    }

    GROUP_BARRIER(NB_ * (t + 2));
  }
#undef GROUP_BARRIER
}

// ---------------------------------------------------------------------------
extern "C" void kernel_launch(void* const* d_in, const int* in_sizes, int n_in,
                              void* d_out, int out_size, void* d_ws,
                              size_t ws_size, hipStream_t stream) {
  const float* x_t = (const float*)d_in[0];
  const float* h0  = (const float*)d_in[1];
  const float* c0  = (const float*)d_in[2];
  const float* We  = (const float*)d_in[3];
  const float* be  = (const float*)d_in[4];
  const float* Wf  = (const float*)d_in[5];
  const float* bf_ = (const float*)d_in[6];
  const float* Wi  = (const float*)d_in[7];
  const float* bi  = (const float*)d_in[8];
  const float* Wg  = (const float*)d_in[9];
  const float* bg  = (const float*)d_in[10];
  const float* Wo  = (const float*)d_in[11];
  const float* bo  = (const float*)d_in[12];
  const float* Rf  = (const float*)d_in[13];
  const float* Ri  = (const float*)d_in[14];
  const float* Rg  = (const float*)d_in[15];
  const float* Ro  = (const float*)d_in[16];
  float* out = (float*)d_out;

  // workspace layout
  char* ws = (char*)d_ws;
  unsigned* cnt = (unsigned*)ws;                                  // 2048 B
  __hip_bfloat16* hbuf = (__hip_bfloat16*)(ws + 4096);            // 262144 B
  __hip_bfloat16* Web  = (__hip_bfloat16*)(ws + 4096 + 262144);   // 262144 B
  __hip_bfloat16* xe   = (__hip_bfloat16*)(ws + 4096 + 2 * 262144);

  hipMemsetAsync(cnt, 0, 2048, stream);

  cvt_we<<<(E_ * DIM_ + 255) / 256, 256, 0, stream>>>(We, Web, E_ * DIM_);

  embed_gemm<<<(B_ * T_) / 32, 256, 0, stream>>>(x_t, Web, be, xe);

  const size_t lds_bytes = 64 * WROW * sizeof(short);  // 132096
  lstm_persist<<<NG_ * NB_, 256, lds_bytes, stream>>>(
      h0, c0, Wi, bi, Wf, bf_, Wg, bg, Wo, bo, Ri, Rf, Rg, Ro, xe, hbuf, cnt,
      out);
}

// Round 3
// 1853.229 us; speedup vs baseline: 11.1813x; 11.1813x over previous
//
#include <hip/hip_runtime.h>
#include <hip/hip_bf16.h>

#define B_ 128
#define T_ 512
#define DIM_ 256
#define E_ 512
#define H_ 512
#define NB_ 32        // blocks per batch-group (sync domain)
#define NG_ 8         // batch groups
#define WROW 1032     // padded LDS row stride (1024 + 8) in bf16 elems

typedef __attribute__((ext_vector_type(8))) short short8;
typedef __attribute__((ext_vector_type(4))) float floatx4;
typedef unsigned long long ull_t;

__device__ __forceinline__ float sigmoidf_(float x) {
  return 1.0f / (1.0f + __expf(-x));
}

__device__ __forceinline__ short f2bs(float f) {
  __hip_bfloat16 h = __float2bfloat16(f);
  return *reinterpret_cast<short*>(&h);
}

// ---------------------------------------------------------------------------
// Kernel 0: convert We (fp32) -> bf16 workspace copy.
// ---------------------------------------------------------------------------
__global__ __launch_bounds__(256) void cvt_we(const float* __restrict__ src,
                                              __hip_bfloat16* __restrict__ dst,
                                              int n) {
  int i = blockIdx.x * 256 + threadIdx.x;
  if (i < n) dst[i] = __float2bfloat16(src[i]);
}

// ---------------------------------------------------------------------------
// Kernel 1: xe[b*T+t][e] = sum_d x_t[b,t,d] * We[e,d] + be[e]   (bf16 out)
// ---------------------------------------------------------------------------
__global__ __launch_bounds__(256) void embed_gemm(
    const float* __restrict__ A,             // x_t  [65536][256] fp32
    const __hip_bfloat16* __restrict__ W,    // Web  [512][256] bf16
    const float* __restrict__ bias,          // be   [512] fp32
    __hip_bfloat16* __restrict__ C)          // xe   [65536][512] bf16
{
  const int tid = threadIdx.x;
  const int lane = tid & 63;
  const int w = tid >> 6;
  const int q = lane >> 4;
  const int l15 = lane & 15;
  const int m0 = blockIdx.x * 32 + (w >> 1) * 16;
  const int n0 = (w & 1) * 256;

  const float* a_base = A + (size_t)(m0 + l15) * DIM_ + q * 8;

  floatx4 acc[16];
#pragma unroll
  for (int j = 0; j < 16; ++j) acc[j] = (floatx4){0.f, 0.f, 0.f, 0.f};

  for (int ks = 0; ks < 8; ++ks) {
    const float* ap = a_base + ks * 32;
    short8 a;
#pragma unroll
    for (int j = 0; j < 8; ++j) a[j] = f2bs(ap[j]);
    short8 bf[16];
#pragma unroll
    for (int j = 0; j < 16; ++j) {
      const short* b_ptr =
          (const short*)W + (n0 + j * 16 + l15) * DIM_ + ks * 32 + q * 8;
      bf[j] = *(const short8*)b_ptr;
    }
#pragma unroll
    for (int j = 0; j < 16; ++j)
      acc[j] = __builtin_amdgcn_mfma_f32_16x16x32_bf16(a, bf[j], acc[j], 0, 0, 0);
  }

#pragma unroll
  for (int j = 0; j < 16; ++j) {
    const int col = n0 + j * 16 + l15;
    const float bv = bias[col];
#pragma unroll
    for (int r = 0; r < 4; ++r) {
      const int row = m0 + q * 4 + r;
      C[(size_t)row * E_ + col] = __float2bfloat16(acc[j][r] + bv);
    }
  }
}

// ---------------------------------------------------------------------------
// Relaxed-atomic group barrier: NO fences (fences on gfx950 emit full L2
// writeback/invalidate -> ~40us/step). Visibility of prior stores is via
// __syncthreads' implicit s_waitcnt vmcnt(0); cross-block data itself moves
// through relaxed agent-scope atomics (performed at the device-coherent
// point / Infinity Cache), so no cache maintenance is needed.
// ---------------------------------------------------------------------------
__device__ __forceinline__ void group_barrier(unsigned* cnt_g, unsigned target,
                                              int tid) {
  __syncthreads();  // drains vmcnt(0): prior atomic h-stores globally visible
  if (tid == 0) {
    __hip_atomic_fetch_add(cnt_g, 1u, __ATOMIC_RELAXED,
                           __HIP_MEMORY_SCOPE_AGENT);
    while (__hip_atomic_load(cnt_g, __ATOMIC_RELAXED,
                             __HIP_MEMORY_SCOPE_AGENT) < target)
      __builtin_amdgcn_s_sleep(1);
  }
  __syncthreads();
}

// ---------------------------------------------------------------------------
// Kernel 2: persistent LSTM. 256 blocks (1/CU), 256 thr.
// block = (group g = blk&7, slice jb = blk>>3): batches [g*16,g*16+16),
// dims [jb*16, jb*16+16), all 4 gates. Weights [64 rows x 1024 K] in LDS.
// Wave w: K-range [w*256,(w+1)*256): waves 0,1 -> xe (W), 2,3 -> h (R).
// h exchanged via relaxed agent atomics (u32 store / u64 load) in hbuf.
// ---------------------------------------------------------------------------
__global__ __launch_bounds__(256, 1) void lstm_persist(
    const float* __restrict__ h0,
    const float* __restrict__ c0,
    const float* __restrict__ Wi_, const float* __restrict__ bi_,
    const float* __restrict__ Wf_, const float* __restrict__ bf_,
    const float* __restrict__ Wg_, const float* __restrict__ bg_,
    const float* __restrict__ Wo_, const float* __restrict__ bo_,
    const float* __restrict__ Ri_, const float* __restrict__ Rf_,
    const float* __restrict__ Rg_, const float* __restrict__ Ro_,
    const __hip_bfloat16* __restrict__ xe,   // [B*T][E] bf16
    unsigned* __restrict__ hbuf32,           // [2][B][H/2] packed 2xbf16
    unsigned* __restrict__ cnt,              // group counters, stride 64 uints
    float* __restrict__ out)                 // hidden_seq | h_last | c_last
{
  extern __shared__ short wts[];             // 64 * WROW bf16 = 132096 B
  __shared__ float pbuf[4][4][16][16];       // [wave][gate][m][n] partials
  __shared__ float cbuf[16][16];             // fp32 cell state slice
  __shared__ float bias_s[4][16];

  const int tid = threadIdx.x;
  const int lane = tid & 63;
  const int w = tid >> 6;
  const int q = lane >> 4;
  const int l15 = lane & 15;
  const int blk = blockIdx.x;
  const int g = blk & 7;        // batch group
  const int jb = blk >> 3;      // dim slice
  const int b0 = g * 16;
  const int d0 = jb * 16;
  unsigned* cnt_g = cnt + g * 64;
  ull_t* hbuf64 = (ull_t*)hbuf32;

  const float* Wp[4] = {Wi_, Wf_, Wg_, Wo_};
  const float* Rp[4] = {Ri_, Rf_, Rg_, Ro_};
  const float* bp[4] = {bi_, bf_, bg_, bo_};

  // ---- load weights into LDS: row (G*16+dl) = [W_G[d0+dl][0:512] | R_G[...]]
  for (int idx = tid; idx < 64 * 128; idx += 256) {
    const int row = idx >> 7;
    const int ch = idx & 127;
    const int G = row >> 4, dl = row & 15;
    const int k = ch * 8;
    const float* src = (k < 512) ? Wp[G] + (d0 + dl) * E_ + k
                                 : Rp[G] + (d0 + dl) * H_ + (k - 512);
    short8 v;
#pragma unroll
    for (int s = 0; s < 8; ++s) v[s] = f2bs(src[s]);
    *(short8*)&wts[row * WROW + k] = v;
  }
  if (tid < 64) {
    const int G = tid >> 4, n = tid & 15;
    bias_s[G][n] = bp[G][d0 + n];
  }
  {
    const int m = tid >> 4, n = tid & 15;
    cbuf[m][n] = c0[(b0 + m) * H_ + d0 + n];
  }
  // h0 -> hbuf buffer 0 (cooperative: 256 blocks x 128 u32 each)
  if (tid < 128) {
    const int e = blk * 256 + tid * 2;
    unsigned pk = (unsigned)(unsigned short)f2bs(h0[e]) |
                  ((unsigned)(unsigned short)f2bs(h0[e + 1]) << 16);
    __hip_atomic_store(&hbuf32[blk * 128 + tid], pk, __ATOMIC_RELAXED,
                       __HIP_MEMORY_SCOPE_AGENT);
  }

  group_barrier(cnt_g, NB_, tid);  // h0 visible to whole group

  // per-wave pointers
  const short* xbase = (const short*)xe +
      (size_t)(b0 + l15) * T_ * E_ + w * 256 + q * 8;        // valid for w<2

  const int lds_base = l15 * WROW + w * 256 + q * 8;

  short8 cur[8];
  if (w < 2) {
#pragma unroll
    for (int s = 0; s < 8; ++s) cur[s] = *(const short8*)(xbase + s * 32);
  }

  for (int t = 0; t < T_; ++t) {
    if (w >= 2) {
      // read h_t rows via relaxed agent 8B atomic loads (IF$-coherent)
      const ull_t* hb = hbuf64 + (size_t)(t & 1) * (B_ * H_ / 4) +
                        (b0 + l15) * (H_ / 4) + (w - 2) * 64 + q * 2;
#pragma unroll
      for (int s = 0; s < 8; ++s) {
        union { ull_t u[2]; short8 v; } uu;
        uu.u[0] = __hip_atomic_load(hb + s * 8, __ATOMIC_RELAXED,
                                    __HIP_MEMORY_SCOPE_AGENT);
        uu.u[1] = __hip_atomic_load(hb + s * 8 + 1, __ATOMIC_RELAXED,
                                    __HIP_MEMORY_SCOPE_AGENT);
        cur[s] = uu.v;
      }
    }

    floatx4 acc[4];
#pragma unroll
    for (int G = 0; G < 4; ++G) acc[G] = (floatx4){0.f, 0.f, 0.f, 0.f};

#pragma unroll
    for (int s = 0; s < 8; ++s) {
#pragma unroll
      for (int G = 0; G < 4; ++G) {
        short8 b = *(const short8*)&wts[G * 16 * WROW + lds_base + s * 32];
        acc[G] = __builtin_amdgcn_mfma_f32_16x16x32_bf16(cur[s], b, acc[G], 0, 0, 0);
      }
    }

    // prefetch next step's xe fragments (read-only: safe across barrier)
    if (w < 2 && t + 1 < T_) {
      const short* xp = xbase + (size_t)(t + 1) * E_;
#pragma unroll
      for (int s = 0; s < 8; ++s) cur[s] = *(const short8*)(xp + s * 32);
    }

    // write partial sums to LDS
#pragma unroll
    for (int G = 0; G < 4; ++G)
#pragma unroll
      for (int r = 0; r < 4; ++r)
        pbuf[w][G][q * 4 + r][l15] = acc[G][r];
    __syncthreads();

    // combine + activations: thread tid -> (m = tid>>4, n = tid&15)
    {
      const int m = tid >> 4, n = tid & 15;
      float pre[4];
#pragma unroll
      for (int G = 0; G < 4; ++G)
        pre[G] = pbuf[0][G][m][n] + pbuf[1][G][m][n] + pbuf[2][G][m][n] +
                 pbuf[3][G][m][n] + bias_s[G][n];
      const float iv = sigmoidf_(pre[0]);
      const float fv = sigmoidf_(pre[1]);
      const float gv = tanhf(pre[2]);
      const float ov = sigmoidf_(pre[3]);
      const float c = gv * iv + fv * cbuf[m][n];
      cbuf[m][n] = c;
      const float h = ov * tanhf(c);

      // pack 2xbf16 with lane n^1 (same wave) and atomic-store (relaxed agent)
      unsigned hv = (unsigned)(unsigned short)f2bs(h);
      unsigned ov2 = __shfl_xor(hv, 1);
      if ((n & 1) == 0) {
        unsigned pk = hv | (ov2 << 16);
        __hip_atomic_store(
            &hbuf32[((t + 1) & 1) * (B_ * H_ / 2) + (b0 + m) * (H_ / 2) +
                    ((d0 + n) >> 1)],
            pk, __ATOMIC_RELAXED, __HIP_MEMORY_SCOPE_AGENT);
      }

      out[((size_t)(b0 + m) * T_ + t) * H_ + d0 + n] = h;
      if (t == T_ - 1) {
        out[(size_t)B_ * T_ * H_ + (b0 + m) * H_ + d0 + n] = h;
        out[(size_t)B_ * T_ * H_ + B_ * H_ + (b0 + m) * H_ + d0 + n] = c;
      }
    }

    group_barrier(cnt_g, NB_ * (t + 2), tid);
  }
}

// ---------------------------------------------------------------------------
extern "C" void kernel_launch(void* const* d_in, const int* in_sizes, int n_in,
                              void* d_out, int out_size, void* d_ws,
                              size_t ws_size, hipStream_t stream) {
  const float* x_t = (const float*)d_in[0];
  const float* h0  = (const float*)d_in[1];
  const float* c0  = (const float*)d_in[2];
  const float* We  = (const float*)d_in[3];
  const float* be  = (const float*)d_in[4];
  const float* Wf  = (const float*)d_in[5];
  const float* bf_ = (const float*)d_in[6];
  const float* Wi  = (const float*)d_in[7];
  const float* bi  = (const float*)d_in[8];
  const float* Wg  = (const float*)d_in[9];
  const float* bg  = (const float*)d_in[10];
  const float* Wo  = (const float*)d_in[11];
  const float* bo  = (const float*)d_in[12];
  const float* Rf  = (const float*)d_in[13];
  const float* Ri  = (const float*)d_in[14];
  const float* Rg  = (const float*)d_in[15];
  const float* Ro  = (const float*)d_in[16];
  float* out = (float*)d_out;

  // workspace layout
  char* ws = (char*)d_ws;
  unsigned* cnt = (unsigned*)ws;                                  // 2048 B
  unsigned* hbuf = (unsigned*)(ws + 4096);                        // 262144 B
  __hip_bfloat16* Web  = (__hip_bfloat16*)(ws + 4096 + 262144);   // 262144 B
  __hip_bfloat16* xe   = (__hip_bfloat16*)(ws + 4096 + 2 * 262144);

  hipMemsetAsync(cnt, 0, 2048, stream);

  cvt_we<<<(E_ * DIM_ + 255) / 256, 256, 0, stream>>>(We, Web, E_ * DIM_);

  embed_gemm<<<(B_ * T_) / 32, 256, 0, stream>>>(x_t, Web, be, xe);

  const size_t lds_bytes = 64 * WROW * sizeof(short);  // 132096
  lstm_persist<<<NG_ * NB_, 256, lds_bytes, stream>>>(
      h0, c0, Wi, bi, Wf, bf_, Wg, bg, Wo, bo, Ri, Rf, Rg, Ro, xe, hbuf, cnt,
      out);
}